// Round 1
// baseline (1194.002 us; speedup 1.0000x reference)
//
#include <hip/hip_runtime.h>

// FilterStage3x3: per-pixel softmax(1x1 conv(f)) -> 3x3 filter of x.
// B=2, F=128, C=3, H=720, W=1280, 9 taps. All fp32. Memory-bound on f (~944 MB).

#define BB 2
#define FF 128
#define CC 3
#define HH 720
#define WW 1280
#define PPT 4              // pixels per thread (float4 along W)
#define BLOCK 256

__global__ __launch_bounds__(BLOCK) void filter3x3_kernel(
    const float* __restrict__ f,
    const float* __restrict__ x,
    const float* __restrict__ Wc,
    const float* __restrict__ bc,
    float* __restrict__ out)
{
    __shared__ float sW[9][FF];   // [tap][channel]
    __shared__ float sb[9];

    const int tid = threadIdx.x;
    for (int i = tid; i < 9 * FF; i += BLOCK) sW[i / FF][i % FF] = Wc[i];
    if (tid < 9) sb[tid] = bc[tid];
    __syncthreads();

    // thread -> (b, h, w4)
    const int t   = blockIdx.x * BLOCK + tid;   // grid sized exactly: no guard needed
    const int WG  = WW / PPT;                   // 320 groups per row
    const int w4  = t % WG;
    const int tmp = t / WG;
    const int h   = tmp % HH;
    const int b   = tmp / HH;
    const int w   = w4 * PPT;

    // ---- 1x1 conv: 9 logits x 4 pixels ----
    float acc[9][PPT];
    #pragma unroll
    for (int o = 0; o < 9; ++o) {
        const float bv = sb[o];
        #pragma unroll
        for (int p = 0; p < PPT; ++p) acc[o][p] = bv;
    }

    const size_t planeF = (size_t)HH * WW;      // 921600
    const float* fp = f + ((size_t)b * FF * HH + h) * WW + w;

    #pragma unroll 4
    for (int ch = 0; ch < FF; ++ch) {
        const float4 fv = *(const float4*)(fp + (size_t)ch * planeF);
        #pragma unroll
        for (int o = 0; o < 9; ++o) {
            const float wv = sW[o][ch];
            acc[o][0] = fmaf(fv.x, wv, acc[o][0]);
            acc[o][1] = fmaf(fv.y, wv, acc[o][1]);
            acc[o][2] = fmaf(fv.z, wv, acc[o][2]);
            acc[o][3] = fmaf(fv.w, wv, acc[o][3]);
        }
    }

    // ---- softmax over the 9 taps, in place ----
    #pragma unroll
    for (int p = 0; p < PPT; ++p) {
        float m = acc[0][p];
        #pragma unroll
        for (int o = 1; o < 9; ++o) m = fmaxf(m, acc[o][p]);
        float s = 0.f;
        #pragma unroll
        for (int o = 0; o < 9; ++o) {
            const float e = __expf(acc[o][p] - m);
            acc[o][p] = e;
            s += e;
        }
        const float inv = 1.f / s;
        #pragma unroll
        for (int o = 0; o < 9; ++o) acc[o][p] *= inv;
    }

    // ---- 3x3 neighborhood combine of x (zero-padded borders) ----
    #pragma unroll
    for (int c = 0; c < CC; ++c) {
        float o0 = 0.f, o1 = 0.f, o2 = 0.f, o3 = 0.f;
        #pragma unroll
        for (int dy = 0; dy < 3; ++dy) {
            const int row = h + dy - 1;
            const bool vr = (row >= 0) && (row < HH);
            const float* xr = x + ((size_t)(b * CC + c) * HH + row) * WW;
            float xv[PPT + 2];                  // columns w-1 .. w+4
            #pragma unroll
            for (int j = 0; j < PPT + 2; ++j) {
                const int col = w - 1 + j;
                xv[j] = (vr && col >= 0 && col < WW) ? xr[col] : 0.f;
            }
            #pragma unroll
            for (int dx = 0; dx < 3; ++dx) {
                const int o = dy * 3 + dx;
                o0 = fmaf(acc[o][0], xv[dx + 0], o0);
                o1 = fmaf(acc[o][1], xv[dx + 1], o1);
                o2 = fmaf(acc[o][2], xv[dx + 2], o2);
                o3 = fmaf(acc[o][3], xv[dx + 3], o3);
            }
        }
        float4 ov = make_float4(o0, o1, o2, o3);
        *(float4*)(out + ((size_t)(b * CC + c) * HH + h) * WW + w) = ov;
    }
}

extern "C" void kernel_launch(void* const* d_in, const int* in_sizes, int n_in,
                              void* d_out, int out_size, void* d_ws, size_t ws_size,
                              hipStream_t stream) {
    const float* f  = (const float*)d_in[0];
    const float* x  = (const float*)d_in[1];
    const float* Wc = (const float*)d_in[2];
    const float* bc = (const float*)d_in[3];
    float* out = (float*)d_out;

    const int total_threads = BB * HH * (WW / PPT);   // 460800
    const int grid = total_threads / BLOCK;           // 1800, exact
    filter3x3_kernel<<<grid, BLOCK, 0, stream>>>(f, x, Wc, bc, out);
}